// Round 1
// baseline (461.816 us; speedup 1.0000x reference)
//
#include <hip/hip_runtime.h>
#include <math.h>

// Problem constants
#define N_   128
#define S_   1024
#define D_   128
#define SD_  (S_ * D_)     // 131072
#define F_   (3 * D_)      // 384

// pe(s): a = s>>5, c = s&31, j2 = c&~1; arg = pi*a*1000^(-j2/128); sin if c even else cos
__device__ __forceinline__ float pe_scale(int s) {
    int a = s >> 5;
    int c = s & 31;
    double rexp = pow(1000.0, -(double)(c & ~1) / 128.0);
    double arg = M_PI * (double)a * rexp;
    return (float)((c & 1) ? cos(arg) : sin(arg));
}

// ---------------------------------------------------------------------------
// K1: scores[n,n'] += sum_{s in block} sum_r q_s[n,r] * k_s[n',r]   (raw, unscaled)
// grid 512 blocks x 256 threads; block handles s in {2b, 2b+1}
// LDS: Wlds[32][132] (16.9KB) + qk[2][128][33] (33.8KB) = 50.7KB
// ---------------------------------------------------------------------------
__global__ __launch_bounds__(256) void k_scores(const float* __restrict__ x,
                                                const float* __restrict__ W,
                                                const float* __restrict__ b,
                                                float* __restrict__ scores) {
    __shared__ float Wlds[32][132];
    __shared__ float qk[2][128][33];

    const int t  = threadIdx.x;
    const int ti = t >> 4;    // 0..15 -> score rows ti + 16*i
    const int tj = t & 15;    // 0..15 -> score cols tj + 16*j
    const int rq = t & 7;     // r-quad within 32-chunk (phase QK)
    const int nq = t >> 3;    // 0..31 -> n rows nq*4 + i (phase QK)

    float acc[8][8];
#pragma unroll
    for (int i = 0; i < 8; ++i)
#pragma unroll
        for (int j = 0; j < 8; ++j) acc[i][j] = 0.0f;

    const int s0 = blockIdx.x * 2;

    for (int si = 0; si < 2; ++si) {
        const int s = s0 + si;
        const float ps = pe_scale(s);
        const float* xs_base = x + (size_t)s * D_;   // + n*SD_ + d

        for (int rc = 0; rc < 4; ++rc) {
            for (int w = 0; w < 2; ++w) {
                __syncthreads();
                // cooperative load of 32 W-rows (3*(rc*32+row)+w) into Wlds[row][d]
                {
                    const int row = t >> 3;           // 0..31
                    const int cb  = (t & 7) * 16;     // 0,16,...,112
                    const float* src = W + (size_t)(3 * (rc * 32 + row) + w) * D_ + cb;
                    float4 v0 = *(const float4*)(src);
                    float4 v1 = *(const float4*)(src + 4);
                    float4 v2 = *(const float4*)(src + 8);
                    float4 v3 = *(const float4*)(src + 12);
                    float* dst = &Wlds[row][cb];
                    dst[0]=v0.x; dst[1]=v0.y; dst[2]=v0.z; dst[3]=v0.w;
                    dst[4]=v1.x; dst[5]=v1.y; dst[6]=v1.z; dst[7]=v1.w;
                    dst[8]=v2.x; dst[9]=v2.y; dst[10]=v2.z; dst[11]=v2.w;
                    dst[12]=v3.x; dst[13]=v3.y; dst[14]=v3.z; dst[15]=v3.w;
                }
                __syncthreads();
                // compute q (w=0) or k (w=1) chunk: thread -> 4 n-rows x 4 r-cols
                float vacc[4][4];
#pragma unroll
                for (int i = 0; i < 4; ++i)
#pragma unroll
                    for (int j = 0; j < 4; ++j) vacc[i][j] = 0.0f;

                for (int dc = 0; dc < D_; dc += 8) {
                    float xr[4][8];
                    float wr[4][8];
#pragma unroll
                    for (int i = 0; i < 4; ++i) {
                        const float* xp = xs_base + (size_t)(nq * 4 + i) * SD_ + dc;
                        float4 u0 = *(const float4*)(xp);
                        float4 u1 = *(const float4*)(xp + 4);
                        xr[i][0]=u0.x; xr[i][1]=u0.y; xr[i][2]=u0.z; xr[i][3]=u0.w;
                        xr[i][4]=u1.x; xr[i][5]=u1.y; xr[i][6]=u1.z; xr[i][7]=u1.w;
                    }
#pragma unroll
                    for (int j = 0; j < 4; ++j) {
                        const float* wp = &Wlds[rq * 4 + j][dc];
                        float4 u0 = *(const float4*)(wp);
                        float4 u1 = *(const float4*)(wp + 4);
                        wr[j][0]=u0.x; wr[j][1]=u0.y; wr[j][2]=u0.z; wr[j][3]=u0.w;
                        wr[j][4]=u1.x; wr[j][5]=u1.y; wr[j][6]=u1.z; wr[j][7]=u1.w;
                    }
#pragma unroll
                    for (int dd = 0; dd < 8; ++dd)
#pragma unroll
                        for (int i = 0; i < 4; ++i)
#pragma unroll
                            for (int j = 0; j < 4; ++j)
                                vacc[i][j] += xr[i][dd] * wr[j][dd];
                }
                // store with bias + pe scale (pe multiplies x only, not bias)
#pragma unroll
                for (int i = 0; i < 4; ++i)
#pragma unroll
                    for (int j = 0; j < 4; ++j) {
                        const float bias = b[3 * (rc * 32 + rq * 4 + j) + w];
                        qk[w][nq * 4 + i][rq * 4 + j] = bias + ps * vacc[i][j];
                    }
            }
            __syncthreads();
            // phase S: accumulate 8x8 tile over the 32 r's of this chunk
            for (int r = 0; r < 32; ++r) {
                float qv[8], kv[8];
#pragma unroll
                for (int i = 0; i < 8; ++i) qv[i] = qk[0][ti + 16 * i][r];
#pragma unroll
                for (int j = 0; j < 8; ++j) kv[j] = qk[1][tj + 16 * j][r];
#pragma unroll
                for (int i = 0; i < 8; ++i)
#pragma unroll
                    for (int j = 0; j < 8; ++j) acc[i][j] += qv[i] * kv[j];
            }
        }
    }

#pragma unroll
    for (int i = 0; i < 8; ++i)
#pragma unroll
        for (int j = 0; j < 8; ++j)
            atomicAdd(&scores[(ti + 16 * i) * N_ + (tj + 16 * j)], acc[i][j]);
}

// ---------------------------------------------------------------------------
// K2: attn = softmax(scores / sqrt(128)) per row. grid 128 x 128 threads
// ---------------------------------------------------------------------------
__global__ void k_softmax(const float* __restrict__ scores, float* __restrict__ attn) {
    const int n = blockIdx.x;
    const int t = threadIdx.x;
    float v = scores[n * N_ + t] * 0.08838834764831845f;  // 1/sqrt(128)

    __shared__ float red[2];
    __shared__ float red2[2];

    float m = v;
#pragma unroll
    for (int o = 32; o > 0; o >>= 1) m = fmaxf(m, __shfl_xor(m, o));
    if ((t & 63) == 0) red[t >> 6] = m;
    __syncthreads();
    m = fmaxf(red[0], red[1]);

    float e = expf(v - m);
    float sum = e;
#pragma unroll
    for (int o = 32; o > 0; o >>= 1) sum += __shfl_xor(sum, o);
    if ((t & 63) == 0) red2[t >> 6] = sum;
    __syncthreads();
    sum = red2[0] + red2[1];

    attn[n * N_ + t] = e / sum;
}

// ---------------------------------------------------------------------------
// K3: out[n, s*128 + r] = sum_{n'} attn[n,n'] * v_s[n', r]
// grid 4096 = (s in 1024) x (rc in 4); block 256
// LDS: Wlds[32][132] (16.9KB) + vl[128][36] (18.4KB) = 35.3KB
// ---------------------------------------------------------------------------
__global__ __launch_bounds__(256) void k_out(const float* __restrict__ x,
                                             const float* __restrict__ W,
                                             const float* __restrict__ b,
                                             const float* __restrict__ attn,
                                             float* __restrict__ out) {
    __shared__ float Wlds[32][132];
    __shared__ float vl[128][36];

    const int t  = threadIdx.x;
    const int s  = blockIdx.x >> 2;
    const int rc = blockIdx.x & 3;
    const int rq = t & 7;
    const int nq = t >> 3;   // 0..31

    const float ps = pe_scale(s);
    const float* xs_base = x + (size_t)s * D_;

    // load Wv rows 3*(rc*32+row)+2
    {
        const int row = t >> 3;
        const int cb  = (t & 7) * 16;
        const float* src = W + (size_t)(3 * (rc * 32 + row) + 2) * D_ + cb;
        float4 v0 = *(const float4*)(src);
        float4 v1 = *(const float4*)(src + 4);
        float4 v2 = *(const float4*)(src + 8);
        float4 v3 = *(const float4*)(src + 12);
        float* dst = &Wlds[row][cb];
        dst[0]=v0.x; dst[1]=v0.y; dst[2]=v0.z; dst[3]=v0.w;
        dst[4]=v1.x; dst[5]=v1.y; dst[6]=v1.z; dst[7]=v1.w;
        dst[8]=v2.x; dst[9]=v2.y; dst[10]=v2.z; dst[11]=v2.w;
        dst[12]=v3.x; dst[13]=v3.y; dst[14]=v3.z; dst[15]=v3.w;
    }
    __syncthreads();

    // phase V: v[n, r] = b[3r+2] + ps * sum_d x[n,s,d] * Wv[r,d]
    {
        float vacc[4][4];
#pragma unroll
        for (int i = 0; i < 4; ++i)
#pragma unroll
            for (int j = 0; j < 4; ++j) vacc[i][j] = 0.0f;

        for (int dc = 0; dc < D_; dc += 8) {
            float xr[4][8];
            float wr[4][8];
#pragma unroll
            for (int i = 0; i < 4; ++i) {
                const float* xp = xs_base + (size_t)(nq * 4 + i) * SD_ + dc;
                float4 u0 = *(const float4*)(xp);
                float4 u1 = *(const float4*)(xp + 4);
                xr[i][0]=u0.x; xr[i][1]=u0.y; xr[i][2]=u0.z; xr[i][3]=u0.w;
                xr[i][4]=u1.x; xr[i][5]=u1.y; xr[i][6]=u1.z; xr[i][7]=u1.w;
            }
#pragma unroll
            for (int j = 0; j < 4; ++j) {
                const float* wp = &Wlds[rq * 4 + j][dc];
                float4 u0 = *(const float4*)(wp);
                float4 u1 = *(const float4*)(wp + 4);
                wr[j][0]=u0.x; wr[j][1]=u0.y; wr[j][2]=u0.z; wr[j][3]=u0.w;
                wr[j][4]=u1.x; wr[j][5]=u1.y; wr[j][6]=u1.z; wr[j][7]=u1.w;
            }
#pragma unroll
            for (int dd = 0; dd < 8; ++dd)
#pragma unroll
                for (int i = 0; i < 4; ++i)
#pragma unroll
                    for (int j = 0; j < 4; ++j)
                        vacc[i][j] += xr[i][dd] * wr[j][dd];
        }
#pragma unroll
        for (int i = 0; i < 4; ++i)
#pragma unroll
            for (int j = 0; j < 4; ++j) {
                const float bias = b[3 * (rc * 32 + rq * 4 + j) + 2];
                vl[nq * 4 + i][rq * 4 + j] = bias + ps * vacc[i][j];
            }
    }
    __syncthreads();

    // phase O: out rows n = nq*4+i (4), cols r = rq*4+j (4); contract over n' (128)
    {
        float oacc[4][4];
#pragma unroll
        for (int i = 0; i < 4; ++i)
#pragma unroll
            for (int j = 0; j < 4; ++j) oacc[i][j] = 0.0f;

        for (int np = 0; np < N_; ++np) {
            float av[4];
#pragma unroll
            for (int i = 0; i < 4; ++i) av[i] = attn[(nq * 4 + i) * N_ + np];
            float4 vv = *(const float4*)&vl[np][rq * 4];
#pragma unroll
            for (int i = 0; i < 4; ++i) {
                oacc[i][0] += av[i] * vv.x;
                oacc[i][1] += av[i] * vv.y;
                oacc[i][2] += av[i] * vv.z;
                oacc[i][3] += av[i] * vv.w;
            }
        }
#pragma unroll
        for (int i = 0; i < 4; ++i) {
            float4 w4;
            w4.x = oacc[i][0]; w4.y = oacc[i][1]; w4.z = oacc[i][2]; w4.w = oacc[i][3];
            *(float4*)&out[(size_t)(nq * 4 + i) * SD_ + s * D_ + rc * 32 + rq * 4] = w4;
        }
    }
}

// ---------------------------------------------------------------------------
extern "C" void kernel_launch(void* const* d_in, const int* in_sizes, int n_in,
                              void* d_out, int out_size, void* d_ws, size_t ws_size,
                              hipStream_t stream) {
    const float* x = (const float*)d_in[0];
    const float* W = (const float*)d_in[1];
    const float* b = (const float*)d_in[2];
    float* out    = (float*)d_out;
    float* scores = (float*)d_ws;                 // 128*128 floats
    float* attn   = scores + N_ * N_;             // 128*128 floats

    hipMemsetAsync(scores, 0, N_ * N_ * sizeof(float), stream);

    hipLaunchKernelGGL(k_scores, dim3(512), dim3(256), 0, stream, x, W, b, scores);
    hipLaunchKernelGGL(k_softmax, dim3(N_), dim3(N_), 0, stream, scores, attn);
    hipLaunchKernelGGL(k_out, dim3(4096), dim3(256), 0, stream, x, W, b, attn, out);
}

// Round 2
// 262.248 us; speedup vs baseline: 1.7610x; 1.7610x over previous
//
#include <hip/hip_runtime.h>
#include <math.h>

#define N_   128
#define S_   1024
#define D_   128
#define SD_  (S_ * D_)     // 131072

typedef __attribute__((ext_vector_type(8))) short bf16x8;
typedef __attribute__((ext_vector_type(4))) short bf16x4;
typedef __attribute__((ext_vector_type(4))) float f32x4;
#define MFMA16 __builtin_amdgcn_mfma_f32_16x16x32_bf16

// pe(s): row i = s>>5, col c = s&31; arg = pi*i*1000^(-(c&~1)/128); sin if c even
__device__ __forceinline__ float pe_scale(int s) {
    int i = s >> 5;
    int c = s & 31;
    double rexp = pow(1000.0, -(double)(c & ~1) / 128.0);
    double arg = M_PI * (double)i * rexp;
    return (float)((c & 1) ? cos(arg) : sin(arg));
}

__device__ __forceinline__ unsigned short bf16_rn(float f) {
    unsigned int u = __float_as_uint(f);
    u += 0x7fff + ((u >> 16) & 1);
    return (unsigned short)(u >> 16);
}
__device__ __forceinline__ float bf16_f(unsigned short h) {
    return __uint_as_float(((unsigned int)h) << 16);
}
__device__ __forceinline__ void split2(float f, unsigned short& h, unsigned short& l) {
    h = bf16_rn(f);
    l = bf16_rn(f - bf16_f(h));
}

// ---------------------------------------------------------------------------
// K1: scores[n,n'] += q_s . k_s  via split-bf16 MFMA. grid 512, block 256.
// Each block: 2 consecutive s. LDS ~147KB -> 1 block/CU.
// ---------------------------------------------------------------------------
__global__ __launch_bounds__(256, 1) void k_scores(const float* __restrict__ x,
                                                   const float* __restrict__ W,
                                                   const float* __restrict__ b,
                                                   float* __restrict__ scores) {
    __shared__ unsigned short xs_hi[128 * 136];
    __shared__ unsigned short xs_lo[128 * 136];
    __shared__ unsigned short Wl[4][32 * 136];   // [p*2+h][r][d]
    __shared__ unsigned short qk[4][128 * 40];   // q_hi,q_lo,k_hi,k_lo : [n][r]
    __shared__ float bl[384];

    const int t    = threadIdx.x;
    const int lane = t & 63;
    const int wv   = t >> 6;        // wave 0..3
    const int lid  = lane & 15;
    const int quad = lane >> 4;

    if (t < 128) { bl[t] = b[t]; bl[t + 128] = b[t + 128]; bl[t + 256] = b[t + 256]; }

    const f32x4 fzero = {0.f, 0.f, 0.f, 0.f};
    f32x4 sacc[2][8];
#pragma unroll
    for (int i = 0; i < 2; ++i)
#pragma unroll
        for (int j = 0; j < 8; ++j) sacc[i][j] = fzero;

    for (int si = 0; si < 2; ++si) {
        const int s = blockIdx.x * 2 + si;
        const float ps = pe_scale(s);
        __syncthreads();
        // ---- stage xs = x[:, s, :] * ps as hi/lo bf16 ----
        {
            const int n0 = t >> 5;             // 0..7
            const int d0 = (t & 31) * 4;
            const float* xp = x + (size_t)s * D_ + d0;
#pragma unroll
            for (int i = 0; i < 16; ++i) {
                const int n = i * 8 + n0;
                float4 v = *(const float4*)(xp + (size_t)n * SD_);
                unsigned short h0, h1, h2, h3, l0, l1, l2, l3;
                split2(v.x * ps, h0, l0); split2(v.y * ps, h1, l1);
                split2(v.z * ps, h2, l2); split2(v.w * ps, h3, l3);
                bf16x4 hv = {(short)h0, (short)h1, (short)h2, (short)h3};
                bf16x4 lv = {(short)l0, (short)l1, (short)l2, (short)l3};
                *(bf16x4*)&xs_hi[n * 136 + d0] = hv;
                *(bf16x4*)&xs_lo[n * 136 + d0] = lv;
            }
        }

        for (int rc = 0; rc < 4; ++rc) {
            __syncthreads();
            // ---- stage W rows 3*(rc*32+m)+p, p in {0,1}, split hi/lo ----
            {
                const int u  = t >> 2;         // 0..63
                const int m  = u >> 1;         // 0..31
                const int p  = u & 1;
                const int c0 = (t & 3) * 32;
                const float* wp = W + (size_t)(3 * (rc * 32 + m) + p) * D_ + c0;
                unsigned short* dh = &Wl[p * 2 + 0][m * 136 + c0];
                unsigned short* dl = &Wl[p * 2 + 1][m * 136 + c0];
#pragma unroll
                for (int i = 0; i < 8; ++i) {
                    float4 v = *(const float4*)(wp + i * 4);
                    unsigned short h0, h1, h2, h3, l0, l1, l2, l3;
                    split2(v.x, h0, l0); split2(v.y, h1, l1);
                    split2(v.z, h2, l2); split2(v.w, h3, l3);
                    bf16x4 hv = {(short)h0, (short)h1, (short)h2, (short)h3};
                    bf16x4 lv = {(short)l0, (short)l1, (short)l2, (short)l3};
                    *(bf16x4*)(dh + i * 4) = hv;
                    *(bf16x4*)(dl + i * 4) = lv;
                }
            }
            __syncthreads();
            // ---- projection qT = Wp @ xs^T (split, 3 terms), p=0:q p=1:k ----
            for (int p = 0; p < 2; ++p) {
                f32x4 pacc[2][2];
                pacc[0][0] = fzero; pacc[0][1] = fzero;
                pacc[1][0] = fzero; pacc[1][1] = fzero;
#pragma unroll
                for (int ks = 0; ks < 4; ++ks) {
                    const int kofs = ks * 32 + quad * 8;
                    bf16x8 ah[2], al[2], bh[2], blo[2];
#pragma unroll
                    for (int mt = 0; mt < 2; ++mt) {
                        ah[mt] = *(const bf16x8*)&Wl[p * 2 + 0][(mt * 16 + lid) * 136 + kofs];
                        al[mt] = *(const bf16x8*)&Wl[p * 2 + 1][(mt * 16 + lid) * 136 + kofs];
                    }
#pragma unroll
                    for (int nt = 0; nt < 2; ++nt) {
                        const int row = (wv * 2 + nt) * 16 + lid;
                        bh[nt]  = *(const bf16x8*)&xs_hi[row * 136 + kofs];
                        blo[nt] = *(const bf16x8*)&xs_lo[row * 136 + kofs];
                    }
#pragma unroll
                    for (int mt = 0; mt < 2; ++mt)
#pragma unroll
                        for (int nt = 0; nt < 2; ++nt) {
                            pacc[mt][nt] = MFMA16(ah[mt], bh[nt],  pacc[mt][nt], 0, 0, 0);
                            pacc[mt][nt] = MFMA16(ah[mt], blo[nt], pacc[mt][nt], 0, 0, 0);
                            pacc[mt][nt] = MFMA16(al[mt], bh[nt],  pacc[mt][nt], 0, 0, 0);
                        }
                }
                // epilogue: + bias, split into hi/lo, b64 write into qk[n][r]
#pragma unroll
                for (int mt = 0; mt < 2; ++mt)
#pragma unroll
                    for (int nt = 0; nt < 2; ++nt) {
                        const int n = (wv * 2 + nt) * 16 + lid;
                        unsigned short hh[4], ll[4];
#pragma unroll
                        for (int r = 0; r < 4; ++r) {
                            const int rg = rc * 32 + mt * 16 + quad * 4 + r;
                            float qv = pacc[mt][nt][r] + bl[3 * rg + p];
                            split2(qv, hh[r], ll[r]);
                        }
                        bf16x4 hv = {(short)hh[0], (short)hh[1], (short)hh[2], (short)hh[3]};
                        bf16x4 lv = {(short)ll[0], (short)ll[1], (short)ll[2], (short)ll[3]};
                        *(bf16x4*)&qk[p * 2 + 0][n * 40 + mt * 16 + quad * 4] = hv;
                        *(bf16x4*)&qk[p * 2 + 1][n * 40 + mt * 16 + quad * 4] = lv;
                    }
            }
            __syncthreads();
            // ---- scores += q @ k^T over this 32-r chunk (split, 3 terms) ----
            {
                bf16x8 qh[2], ql[2];
#pragma unroll
                for (int mt = 0; mt < 2; ++mt) {
                    const int row = wv * 32 + mt * 16 + lid;
                    qh[mt] = *(const bf16x8*)&qk[0][row * 40 + quad * 8];
                    ql[mt] = *(const bf16x8*)&qk[1][row * 40 + quad * 8];
                }
#pragma unroll
                for (int ntp = 0; ntp < 8; ++ntp) {
                    const int row = ntp * 16 + lid;
                    bf16x8 kh = *(const bf16x8*)&qk[2][row * 40 + quad * 8];
                    bf16x8 kl = *(const bf16x8*)&qk[3][row * 40 + quad * 8];
#pragma unroll
                    for (int mt = 0; mt < 2; ++mt) {
                        sacc[mt][ntp] = MFMA16(qh[mt], kh, sacc[mt][ntp], 0, 0, 0);
                        sacc[mt][ntp] = MFMA16(qh[mt], kl, sacc[mt][ntp], 0, 0, 0);
                        sacc[mt][ntp] = MFMA16(ql[mt], kh, sacc[mt][ntp], 0, 0, 0);
                    }
                }
            }
        }
    }
    // ---- atomic accumulate into global scores ----
#pragma unroll
    for (int mt = 0; mt < 2; ++mt)
#pragma unroll
        for (int ntp = 0; ntp < 8; ++ntp)
#pragma unroll
            for (int r = 0; r < 4; ++r) {
                const int n  = wv * 32 + mt * 16 + quad * 4 + r;
                const int np = ntp * 16 + lid;
                atomicAdd(&scores[n * N_ + np], sacc[mt][ntp][r]);
            }
}

// ---------------------------------------------------------------------------
// K2: attn = softmax(scores/sqrt(128)) -> bf16. grid 128 x 128 threads.
// ---------------------------------------------------------------------------
__global__ void k_softmax(const float* __restrict__ scores, unsigned short* __restrict__ attn_bf) {
    const int n = blockIdx.x;
    const int t = threadIdx.x;
    float v = scores[n * N_ + t] * 0.08838834764831845f;

    __shared__ float red[2];
    __shared__ float red2[2];

    float m = v;
#pragma unroll
    for (int o = 32; o > 0; o >>= 1) m = fmaxf(m, __shfl_xor(m, o));
    if ((t & 63) == 0) red[t >> 6] = m;
    __syncthreads();
    m = fmaxf(red[0], red[1]);

    float e = expf(v - m);
    float sum = e;
#pragma unroll
    for (int o = 32; o > 0; o >>= 1) sum += __shfl_xor(sum, o);
    if ((t & 63) == 0) red2[t >> 6] = sum;
    __syncthreads();
    sum = red2[0] + red2[1];

    attn_bf[n * N_ + t] = bf16_rn(e / sum);
}

// ---------------------------------------------------------------------------
// K3: out[n, s*128+r] = sum_n' attn[n,n'] * v_s[n',r]. grid 1024, block 256.
// v-proj split-bf16; PV plain bf16 (outT = vT @ attnT -> dwordx4 stores).
// ---------------------------------------------------------------------------
__global__ __launch_bounds__(256, 1) void k_out(const float* __restrict__ x,
                                                const float* __restrict__ W,
                                                const float* __restrict__ b,
                                                const unsigned short* __restrict__ attn_bf,
                                                float* __restrict__ out) {
    __shared__ unsigned short xs_hi[128 * 136];
    __shared__ unsigned short xs_lo[128 * 136];
    __shared__ unsigned short vT[128 * 136];     // [r][n'] bf16
    __shared__ unsigned short at[128 * 136];     // [n][n'] bf16
    __shared__ unsigned short Wl[2][32 * 136];   // [h][r][d]
    __shared__ float bv[128];

    const int t    = threadIdx.x;
    const int lane = t & 63;
    const int wv   = t >> 6;
    const int lid  = lane & 15;
    const int quad = lane >> 4;
    const int s    = blockIdx.x;
    const float ps = pe_scale(s);

    if (t < 128) bv[t] = b[3 * t + 2];
    // ---- stage attn (bf16) ----
    {
        const int row = t >> 1;
        const int c0  = (t & 1) * 64;
        const unsigned short* ap = attn_bf + row * N_ + c0;
#pragma unroll
        for (int i = 0; i < 8; ++i) {
            bf16x8 av = *(const bf16x8*)(ap + i * 8);
            *(bf16x8*)&at[row * 136 + c0 + i * 8] = av;
        }
    }
    // ---- stage xs ----
    {
        const int n0 = t >> 5;
        const int d0 = (t & 31) * 4;
        const float* xp = x + (size_t)s * D_ + d0;
#pragma unroll
        for (int i = 0; i < 16; ++i) {
            const int n = i * 8 + n0;
            float4 v = *(const float4*)(xp + (size_t)n * SD_);
            unsigned short h0, h1, h2, h3, l0, l1, l2, l3;
            split2(v.x * ps, h0, l0); split2(v.y * ps, h1, l1);
            split2(v.z * ps, h2, l2); split2(v.w * ps, h3, l3);
            bf16x4 hv = {(short)h0, (short)h1, (short)h2, (short)h3};
            bf16x4 lv = {(short)l0, (short)l1, (short)l2, (short)l3};
            *(bf16x4*)&xs_hi[n * 136 + d0] = hv;
            *(bf16x4*)&xs_lo[n * 136 + d0] = lv;
        }
    }

    const f32x4 fzero = {0.f, 0.f, 0.f, 0.f};

    for (int rc = 0; rc < 4; ++rc) {
        __syncthreads();
        // ---- stage Wv rows 3*(rc*32+m)+2 ----
        {
            const int m  = t >> 3;         // 0..31
            const int c0 = (t & 7) * 16;
            const float* wp = W + (size_t)(3 * (rc * 32 + m) + 2) * D_ + c0;
            unsigned short* dh = &Wl[0][m * 136 + c0];
            unsigned short* dl = &Wl[1][m * 136 + c0];
#pragma unroll
            for (int i = 0; i < 4; ++i) {
                float4 v = *(const float4*)(wp + i * 4);
                unsigned short h0, h1, h2, h3, l0, l1, l2, l3;
                split2(v.x, h0, l0); split2(v.y, h1, l1);
                split2(v.z, h2, l2); split2(v.w, h3, l3);
                bf16x4 hv = {(short)h0, (short)h1, (short)h2, (short)h3};
                bf16x4 lv = {(short)l0, (short)l1, (short)l2, (short)l3};
                *(bf16x4*)(dh + i * 4) = hv;
                *(bf16x4*)(dl + i * 4) = lv;
            }
        }
        __syncthreads();
        // ---- v-proj: v = xs @ Wv^T (split), D written transposed into vT ----
        f32x4 vacc[2][2];
        vacc[0][0] = fzero; vacc[0][1] = fzero; vacc[1][0] = fzero; vacc[1][1] = fzero;
#pragma unroll
        for (int ks = 0; ks < 4; ++ks) {
            const int kofs = ks * 32 + quad * 8;
            bf16x8 ah[2], al[2], bh[2], blo[2];
#pragma unroll
            for (int mt = 0; mt < 2; ++mt) {
                const int row = (wv * 2 + mt) * 16 + lid;
                ah[mt] = *(const bf16x8*)&xs_hi[row * 136 + kofs];
                al[mt] = *(const bf16x8*)&xs_lo[row * 136 + kofs];
            }
#pragma unroll
            for (int nt = 0; nt < 2; ++nt) {
                bh[nt]  = *(const bf16x8*)&Wl[0][(nt * 16 + lid) * 136 + kofs];
                blo[nt] = *(const bf16x8*)&Wl[1][(nt * 16 + lid) * 136 + kofs];
            }
#pragma unroll
            for (int mt = 0; mt < 2; ++mt)
#pragma unroll
                for (int nt = 0; nt < 2; ++nt) {
                    vacc[mt][nt] = MFMA16(ah[mt], bh[nt],  vacc[mt][nt], 0, 0, 0);
                    vacc[mt][nt] = MFMA16(ah[mt], blo[nt], vacc[mt][nt], 0, 0, 0);
                    vacc[mt][nt] = MFMA16(al[mt], bh[nt],  vacc[mt][nt], 0, 0, 0);
                }
        }
#pragma unroll
        for (int mt = 0; mt < 2; ++mt)
#pragma unroll
            for (int nt = 0; nt < 2; ++nt) {
                const int r = rc * 32 + nt * 16 + lid;    // vT row
                const float bias = bv[r];
                unsigned short hh[4];
#pragma unroll
                for (int i = 0; i < 4; ++i) hh[i] = bf16_rn(vacc[mt][nt][i] + bias);
                bf16x4 hv = {(short)hh[0], (short)hh[1], (short)hh[2], (short)hh[3]};
                *(bf16x4*)&vT[r * 136 + (wv * 2 + mt) * 16 + quad * 4] = hv;
            }
    }
    __syncthreads();
    // ---- PV: outT = vT @ attnT (plain bf16) ----
    {
        f32x4 oacc[2][8];
#pragma unroll
        for (int i = 0; i < 2; ++i)
#pragma unroll
            for (int j = 0; j < 8; ++j) oacc[i][j] = fzero;
#pragma unroll
        for (int ks = 0; ks < 4; ++ks) {
            const int kofs = ks * 32 + quad * 8;
            bf16x8 a[2];
#pragma unroll
            for (int mt = 0; mt < 2; ++mt)
                a[mt] = *(const bf16x8*)&vT[((wv * 2 + mt) * 16 + lid) * 136 + kofs];
#pragma unroll
            for (int nt = 0; nt < 8; ++nt) {
                bf16x8 bb = *(const bf16x8*)&at[(nt * 16 + lid) * 136 + kofs];
#pragma unroll
                for (int mt = 0; mt < 2; ++mt)
                    oacc[mt][nt] = MFMA16(a[mt], bb, oacc[mt][nt], 0, 0, 0);
            }
        }
#pragma unroll
        for (int mt = 0; mt < 2; ++mt)
#pragma unroll
            for (int nt = 0; nt < 8; ++nt) {
                const int r = (wv * 2 + mt) * 16 + quad * 4;
                const int n = nt * 16 + lid;
                *(float4*)&out[(size_t)n * SD_ + s * D_ + r] = *(float4*)&oacc[mt][nt];
            }
    }
}

// ---------------------------------------------------------------------------
extern "C" void kernel_launch(void* const* d_in, const int* in_sizes, int n_in,
                              void* d_out, int out_size, void* d_ws, size_t ws_size,
                              hipStream_t stream) {
    const float* x = (const float*)d_in[0];
    const float* W = (const float*)d_in[1];
    const float* b = (const float*)d_in[2];
    float* out = (float*)d_out;
    float* scores = (float*)d_ws;                              // 64 KB
    unsigned short* attn_bf = (unsigned short*)((char*)d_ws + N_ * N_ * sizeof(float));  // 32 KB

    hipMemsetAsync(scores, 0, N_ * N_ * sizeof(float), stream);

    hipLaunchKernelGGL(k_scores, dim3(512), dim3(256), 0, stream, x, W, b, scores);
    hipLaunchKernelGGL(k_softmax, dim3(N_), dim3(128), 0, stream, scores, attn_bf);
    hipLaunchKernelGGL(k_out, dim3(1024), dim3(256), 0, stream, x, W, b, attn_bf, out);
}